// Round 3
// baseline (405.666 us; speedup 1.0000x reference)
//
#include <hip/hip_runtime.h>
#include <hip/hip_bf16.h>
#include <stdint.h>

#define N_TOK 32768
#define DIM   1024
#define NC    256
#define GAMMA_F 1e-4f

typedef unsigned short u16;
typedef __attribute__((ext_vector_type(8))) short bf16x8;
typedef __attribute__((ext_vector_type(4))) float f32x4;

// float -> bf16 (round-to-nearest-even); inputs are finite
__device__ __forceinline__ u16 f2b(float f) {
  union { float f; uint32_t u; } c; c.f = f;
  uint32_t u = c.u;
  return (u16)((u + 0x7FFFu + ((u >> 16) & 1u)) >> 16);
}

// async global->LDS, 16B per lane; lds arg must be the wave-uniform chunk base
__device__ __forceinline__ void gll16(const void* g, void* l) {
  __builtin_amdgcn_global_load_lds(
      (const __attribute__((address_space(1))) unsigned int*)g,
      (__attribute__((address_space(3))) unsigned int*)l, 16, 0, 0);
}

// Swizzle scheme for [R][64]-bf16 LDS tiles (128B row = 8 x 16B units):
//   slot (row, u) holds global unit u ^ (row&7)  -> conflict-free b128 reads.

// ---------------------------------------------------------------- K0: X^T -> bf16
__global__ __launch_bounds__(256) void k0_transpose(const float* __restrict__ X,
                                                    u16* __restrict__ TX) {
  __shared__ u16 tile[64][68];
  const int n0 = blockIdx.x * 64;
  const int d0 = blockIdx.y * 64;
  const int t = threadIdx.x;
  const int r = t >> 4;
  const int c4 = (t & 15) * 4;
#pragma unroll
  for (int i = 0; i < 4; ++i) {
    const int row = r + i * 16;
    const float4 v = *reinterpret_cast<const float4*>(&X[(size_t)(n0 + row) * DIM + d0 + c4]);
    tile[row][c4 + 0] = f2b(v.x);
    tile[row][c4 + 1] = f2b(v.y);
    tile[row][c4 + 2] = f2b(v.z);
    tile[row][c4 + 3] = f2b(v.w);
  }
  __syncthreads();
#pragma unroll
  for (int i = 0; i < 4; ++i) {
    const int drow = r + i * 16;
    ushort4 o;
    o.x = tile[c4 + 0][drow];
    o.y = tile[c4 + 1][drow];
    o.z = tile[c4 + 2][drow];
    o.w = tile[c4 + 3][drow];
    *reinterpret_cast<ushort4*>(&TX[(size_t)(d0 + drow) * N_TOK + n0 + c4]) = o;
  }
}

// ---------------------------------------------------------------- K0w: W -> bf16
__global__ __launch_bounds__(256) void k0_convert_w(const float* __restrict__ W,
                                                    u16* __restrict__ Wb) {
  const int idx = (blockIdx.x * 256 + threadIdx.x) * 4;
  const float4 v = *reinterpret_cast<const float4*>(&W[idx]);
  ushort4 o;
  o.x = f2b(v.x); o.y = f2b(v.y); o.z = f2b(v.z); o.w = f2b(v.w);
  *reinterpret_cast<ushort4*>(&Wb[idx]) = o;
}

// ---------------------------------------------------------------- P1: S = X*Wb^T -> softmax -> P, P^T
// BM=64, BN=256 (X read ONCE). 4 waves (2m x 2n). Register softmax (no f32 LDS
// staging): bias folded into acc, n-reduce in reg, frow-reduce via shfl_xor,
// cross-wn via 1KB LDS. LDS = 40KB -> 4 blocks/CU.
__global__ __launch_bounds__(256, 4) void p1_fused(const float* __restrict__ X,
                                                   const u16* __restrict__ Wb,
                                                   const float* __restrict__ bias,
                                                   u16* __restrict__ P,
                                                   u16* __restrict__ PT) {
  __shared__ __align__(16) char smem[40960];       // As 8K | Bs 32K ; epilogue: Su 33280 + red 1K
  u16* As = (u16*)smem;                            // [64][64] bf16, swizzled
  u16* Bs = (u16*)(smem + 8192);                   // [256][64] bf16, swizzled
  const int t = threadIdx.x;
  const int lane = t & 63, wave = t >> 6;
  const int wm = wave & 1, wn = wave >> 1;
  const int id = blockIdx.x;
  const int n0 = ((id & 7) * 64 + (id >> 3)) * 64; // XCD-swizzled (512 blocks)
  const int frow = lane & 15, fq = lane >> 4;
  const int au = t & 7, ar0 = t >> 3;              // A staging: unit, row
  const int bug = (lane & 7) ^ (lane >> 3);        // B staging: swizzled global unit

  f32x4 acc[2][8] = {};
  for (int kt = 0; kt < 16; ++kt) {
    const int k0 = kt * 64;
    // A: X f32 [64][64] -> bf16, swizzled ds_write
#pragma unroll
    for (int h = 0; h < 2; ++h) {
      const int r = ar0 + h * 32;
      const size_t gb = (size_t)(n0 + r) * DIM + k0 + au * 8;
      const float4 v0 = *reinterpret_cast<const float4*>(&X[gb]);
      const float4 v1 = *reinterpret_cast<const float4*>(&X[gb + 4]);
      bf16x8 u;
      u[0] = (short)f2b(v0.x); u[1] = (short)f2b(v0.y);
      u[2] = (short)f2b(v0.z); u[3] = (short)f2b(v0.w);
      u[4] = (short)f2b(v1.x); u[5] = (short)f2b(v1.y);
      u[6] = (short)f2b(v1.z); u[7] = (short)f2b(v1.w);
      *reinterpret_cast<bf16x8*>(&As[r * 64 + ((au ^ (r & 7)) * 8)]) = u;
    }
    // B: Wb [256][64] via global_load_lds, pre-swizzled source
#pragma unroll
    for (int i = 0; i < 8; ++i) {
      const int chunk = wave * 8 + i;
      const int brow = chunk * 8 + (lane >> 3);
      gll16(&Wb[(size_t)brow * DIM + k0 + bug * 8], &Bs[chunk * 512]);
    }
    __syncthreads();
#pragma unroll
    for (int ks = 0; ks < 2; ++ks) {
      bf16x8 af[2], bg[8];
#pragma unroll
      for (int m = 0; m < 2; ++m) {
        const int r = wm * 32 + m * 16 + frow;
        af[m] = *reinterpret_cast<const bf16x8*>(&As[r * 64 + (((ks * 4 + fq) ^ (r & 7)) * 8)]);
      }
#pragma unroll
      for (int n = 0; n < 8; ++n) {
        const int r = wn * 128 + n * 16 + frow;
        bg[n] = *reinterpret_cast<const bf16x8*>(&Bs[r * 64 + (((ks * 4 + fq) ^ (r & 7)) * 8)]);
      }
#pragma unroll
      for (int m = 0; m < 2; ++m)
#pragma unroll
        for (int n = 0; n < 8; ++n)
          acc[m][n] = __builtin_amdgcn_mfma_f32_16x16x32_bf16(af[m], bg[n], acc[m][n], 0, 0, 0);
    }
    __syncthreads();
  }

  // ---- register softmax epilogue
  u16*   Su     = (u16*)smem;                      // [64][260] bf16 (stride 260)
  float* red_mx = (float*)(smem + 33280);          // [64][2]
  float* red_sm = (float*)(smem + 33792);          // [64][2]

  float bias_r[8];
#pragma unroll
  for (int n = 0; n < 8; ++n) bias_r[n] = bias[wn * 128 + n * 16 + frow];
#pragma unroll
  for (int m = 0; m < 2; ++m)
#pragma unroll
    for (int n = 0; n < 8; ++n)
#pragma unroll
      for (int j = 0; j < 4; ++j) acc[m][n][j] += bias_r[n];

  float mx[2][4];
#pragma unroll
  for (int m = 0; m < 2; ++m)
#pragma unroll
    for (int j = 0; j < 4; ++j) {
      float v = acc[m][0][j];
#pragma unroll
      for (int n = 1; n < 8; ++n) v = fmaxf(v, acc[m][n][j]);
#pragma unroll
      for (int s = 1; s < 16; s <<= 1) v = fmaxf(v, __shfl_xor(v, s, 64));
      mx[m][j] = v;
    }
  if (frow == 0) {
#pragma unroll
    for (int m = 0; m < 2; ++m)
#pragma unroll
      for (int j = 0; j < 4; ++j)
        red_mx[(wm * 32 + m * 16 + fq * 4 + j) * 2 + wn] = mx[m][j];
  }
  __syncthreads();

  const float l2e = 1.44269504088896f;
  float psum[2][4];
#pragma unroll
  for (int m = 0; m < 2; ++m)
#pragma unroll
    for (int j = 0; j < 4; ++j) {
      const int row = wm * 32 + m * 16 + fq * 4 + j;
      const float2 r2 = *reinterpret_cast<const float2*>(&red_mx[row * 2]);
      const float M = fmaxf(r2.x, r2.y);
      float s = 0.f;
#pragma unroll
      for (int n = 0; n < 8; ++n) {
        const float e = exp2f((acc[m][n][j] - M) * l2e);
        acc[m][n][j] = e;
        s += e;
      }
#pragma unroll
      for (int ss = 1; ss < 16; ss <<= 1) s += __shfl_xor(s, ss, 64);
      psum[m][j] = s;
    }
  if (frow == 0) {
#pragma unroll
    for (int m = 0; m < 2; ++m)
#pragma unroll
      for (int j = 0; j < 4; ++j)
        red_sm[(wm * 32 + m * 16 + fq * 4 + j) * 2 + wn] = psum[m][j];
  }
  __syncthreads();

#pragma unroll
  for (int m = 0; m < 2; ++m)
#pragma unroll
    for (int j = 0; j < 4; ++j) {
      const int row = wm * 32 + m * 16 + fq * 4 + j;
      const float2 r2 = *reinterpret_cast<const float2*>(&red_sm[row * 2]);
      const float iv = 1.0f / (r2.x + r2.y);
#pragma unroll
      for (int n = 0; n < 8; ++n)
        Su[row * 260 + wn * 128 + n * 16 + frow] = f2b(acc[m][n][j] * iv);
    }
  __syncthreads();

  // P: coalesced, 256 threads x ushort4 = 2KB contiguous per iter
#pragma unroll
  for (int g = 0; g < 16; ++g) {
    const int row = g * 4 + wave;
    const int c = lane * 4;
    const ushort4 v = *reinterpret_cast<const ushort4*>(&Su[row * 260 + c]);
    *reinterpret_cast<ushort4*>(&P[(size_t)(n0 + row) * NC + c]) = v;
  }
  // PT: quarter-wave per c-row, 16 lanes x ushort4 = 128B contiguous
#pragma unroll
  for (int it = 0; it < 16; ++it) {
    const int c = it * 16 + wave * 4 + fq;
    const int n = frow * 4;
    ushort4 o;
    o.x = Su[(n + 0) * 260 + c];
    o.y = Su[(n + 1) * 260 + c];
    o.z = Su[(n + 2) * 260 + c];
    o.w = Su[(n + 3) * 260 + c];
    *reinterpret_cast<ushort4*>(&PT[(size_t)c * N_TOK + n0 + n]) = o;
  }
}

// ---------------------------------------------------------------- P2: PtX^T partials = TX * PT^T (split-K)
// LDS 34KB (epilogue in 64-row halves) -> 4 blocks/CU. XCD-swizzled grid.
__global__ __launch_bounds__(256, 4) void p2_gemm(const u16* __restrict__ TX,
                                                  const u16* __restrict__ PT,
                                                  float* __restrict__ part) {
  __shared__ __align__(16) char smem[34816];       // As 16K + Bs 16K ; Cf half 33792
  u16* As = (u16*)smem;
  u16* Bs = (u16*)(smem + 16384);
  const int t = threadIdx.x;
  const int lane = t & 63, wave = t >> 6;
  const int wm = wave & 1, wn = wave >> 1;
  const int id = blockIdx.x;                       // 512 blocks 1D
  const int swz = (id & 7) * 64 + (id >> 3);
  const int d0 = (swz & 7) * 128;                  // fastest -> blocks share PT tile
  const int sk = (swz >> 3) & 31;
  const int c0 = (swz >> 8) * 128;
  const int frow = lane & 15, fq = lane >> 4;
  const int srow = lane >> 3;
  const int bug = (lane & 7) ^ (lane >> 3);
  f32x4 acc[4][4] = {};
  for (int kt = 0; kt < 16; ++kt) {
    const size_t k0 = (size_t)sk * 1024 + kt * 64;
#pragma unroll
    for (int i = 0; i < 4; ++i) {
      const int chunk = wave * 4 + i;
      const int r = chunk * 8 + srow;
      gll16(&TX[(size_t)(d0 + r) * N_TOK + k0 + bug * 8], &As[chunk * 512]);
      gll16(&PT[(size_t)(c0 + r) * N_TOK + k0 + bug * 8], &Bs[chunk * 512]);
    }
    __syncthreads();
#pragma unroll
    for (int ks = 0; ks < 2; ++ks) {
      bf16x8 af[4], bg[4];
#pragma unroll
      for (int m = 0; m < 4; ++m) {
        const int r = wm * 64 + m * 16 + frow;
        af[m] = *reinterpret_cast<const bf16x8*>(&As[r * 64 + (((ks * 4 + fq) ^ (r & 7)) * 8)]);
      }
#pragma unroll
      for (int n = 0; n < 4; ++n) {
        const int r = wn * 64 + n * 16 + frow;
        bg[n] = *reinterpret_cast<const bf16x8*>(&Bs[r * 64 + (((ks * 4 + fq) ^ (r & 7)) * 8)]);
      }
#pragma unroll
      for (int m = 0; m < 4; ++m)
#pragma unroll
        for (int n = 0; n < 4; ++n)
          acc[m][n] = __builtin_amdgcn_mfma_f32_16x16x32_bf16(af[m], bg[n], acc[m][n], 0, 0, 0);
    }
    __syncthreads();
  }
  // epilogue in two 64-row halves (Cf aliases As+Bs)
  float* Cf = (float*)smem;                        // [64][132]
  float* pl = part + (size_t)sk * (DIM * NC);
  const int cl = (t & 31) * 4;
  const int rq = t >> 5;
#pragma unroll
  for (int h = 0; h < 2; ++h) {
    __syncthreads();
    if (wm == h) {
#pragma unroll
      for (int m = 0; m < 4; ++m)
#pragma unroll
        for (int n = 0; n < 4; ++n) {
          const int rr = m * 16 + fq * 4;
          const int col = wn * 64 + n * 16 + frow;
#pragma unroll
          for (int j = 0; j < 4; ++j)
            Cf[(rr + j) * 132 + col] = acc[m][n][j];
        }
    }
    __syncthreads();
#pragma unroll
    for (int p = 0; p < 8; ++p) {
      const int row = p * 8 + rq;
      const float4 v = *reinterpret_cast<const float4*>(&Cf[row * 132 + cl]);
      *reinterpret_cast<float4*>(&pl[(size_t)(d0 + h * 64 + row) * NC + c0 + cl]) = v;
    }
  }
}

// ---------------------------------------------------------------- K2r: reduce split-K, fold gamma, -> bf16
__global__ __launch_bounds__(256) void k2_reduce(const float* __restrict__ part,
                                                 u16* __restrict__ PtXb) {
  const int g = (blockIdx.x * 256 + threadIdx.x) * 4;
  f32x4 s = {0.f, 0.f, 0.f, 0.f};
#pragma unroll
  for (int p = 0; p < 32; ++p)
    s += *reinterpret_cast<const f32x4*>(&part[(size_t)p * (DIM * NC) + g]);
  ushort4 o;
  o.x = f2b(s[0] * GAMMA_F); o.y = f2b(s[1] * GAMMA_F);
  o.z = f2b(s[2] * GAMMA_F); o.w = f2b(s[3] * GAMMA_F);
  *reinterpret_cast<ushort4*>(&PtXb[g]) = o;
}

// ---------------------------------------------------------------- P3: Out = X + P * PtXb^T
// LDS 34KB (epilogue halves) -> 4 blocks/CU. One d-panel per XCD.
__global__ __launch_bounds__(256, 4) void p3_gemm(const u16* __restrict__ P,
                                                  const u16* __restrict__ PtXb,
                                                  const float* __restrict__ X,
                                                  float* __restrict__ Out) {
  __shared__ __align__(16) char smem[34816];
  u16* As = (u16*)smem;
  u16* Bs = (u16*)(smem + 16384);
  const int t = threadIdx.x;
  const int lane = t & 63, wave = t >> 6;
  const int wm = wave & 1, wn = wave >> 1;
  const int id = blockIdx.x;                       // 2048 blocks 1D
  const int swz = (id & 7) * 256 + (id >> 3);
  const int n0 = (swz & 255) * 128;                // fastest -> PtXb panel L2-resident
  const int d0 = (swz >> 8) * 128;
  const int frow = lane & 15, fq = lane >> 4;
  const int srow = lane >> 3;
  const int bug = (lane & 7) ^ (lane >> 3);
  f32x4 acc[4][4] = {};
  for (int kt = 0; kt < 4; ++kt) {
    const int k0 = kt * 64;
#pragma unroll
    for (int i = 0; i < 4; ++i) {
      const int chunk = wave * 4 + i;
      const int r = chunk * 8 + srow;
      gll16(&P[(size_t)(n0 + r) * NC + k0 + bug * 8], &As[chunk * 512]);
      gll16(&PtXb[(size_t)(d0 + r) * NC + k0 + bug * 8], &Bs[chunk * 512]);
    }
    __syncthreads();
#pragma unroll
    for (int ks = 0; ks < 2; ++ks) {
      bf16x8 af[4], bg[4];
#pragma unroll
      for (int m = 0; m < 4; ++m) {
        const int r = wm * 64 + m * 16 + frow;
        af[m] = *reinterpret_cast<const bf16x8*>(&As[r * 64 + (((ks * 4 + fq) ^ (r & 7)) * 8)]);
      }
#pragma unroll
      for (int n = 0; n < 4; ++n) {
        const int r = wn * 64 + n * 16 + frow;
        bg[n] = *reinterpret_cast<const bf16x8*>(&Bs[r * 64 + (((ks * 4 + fq) ^ (r & 7)) * 8)]);
      }
#pragma unroll
      for (int m = 0; m < 4; ++m)
#pragma unroll
        for (int n = 0; n < 4; ++n)
          acc[m][n] = __builtin_amdgcn_mfma_f32_16x16x32_bf16(af[m], bg[n], acc[m][n], 0, 0, 0);
    }
    __syncthreads();
  }
  // epilogue in two 64-row halves: coalesced float4 X-read + Out-write
  float* Cf = (float*)smem;                        // [64][132]
  const int cl = (t & 31) * 4;
  const int rq = t >> 5;
#pragma unroll
  for (int h = 0; h < 2; ++h) {
    __syncthreads();
    if (wm == h) {
#pragma unroll
      for (int m = 0; m < 4; ++m)
#pragma unroll
        for (int n = 0; n < 4; ++n) {
          const int rr = m * 16 + fq * 4;
          const int col = wn * 64 + n * 16 + frow;
#pragma unroll
          for (int j = 0; j < 4; ++j)
            Cf[(rr + j) * 132 + col] = acc[m][n][j];
        }
    }
    __syncthreads();
#pragma unroll
    for (int p = 0; p < 8; ++p) {
      const int row = p * 8 + rq;
      float4 v = *reinterpret_cast<const float4*>(&Cf[row * 132 + cl]);
      const size_t off = (size_t)(n0 + h * 64 + row) * DIM + d0 + cl;
      const float4 x = *reinterpret_cast<const float4*>(&X[off]);
      v.x += x.x; v.y += x.y; v.z += x.z; v.w += x.w;
      *reinterpret_cast<float4*>(&Out[off]) = v;
    }
  }
}

// ---------------------------------------------------------------- launch
extern "C" void kernel_launch(void* const* d_in, const int* in_sizes, int n_in,
                              void* d_out, int out_size, void* d_ws, size_t ws_size,
                              hipStream_t stream) {
  const float* X = (const float*)d_in[0];
  const float* W = (const float*)d_in[1];
  const float* b = (const float*)d_in[2];
  float* Out = (float*)d_out;
  char* ws = (char*)d_ws;

  // ws layout (bytes): TX 64MB | Wb 0.5MB | PtXb 0.5MB | partials 32MB | P 16MB | PT 16MB
  const size_t OFF_TX   = 0;
  const size_t OFF_WB   = (size_t)64 << 20;
  const size_t OFF_PTXB = OFF_WB + ((size_t)512 << 10);
  const size_t OFF_PART = (size_t)65 << 20;
  const size_t OFF_P    = (size_t)97 << 20;
  const size_t OFF_PT   = (size_t)113 << 20;
  const size_t NEED     = (size_t)129 << 20;
  if (ws_size < NEED) return;

  u16*   TX   = (u16*)(ws + OFF_TX);
  u16*   Wb   = (u16*)(ws + OFF_WB);
  u16*   PtXb = (u16*)(ws + OFF_PTXB);
  float* part = (float*)(ws + OFF_PART);
  u16*   Pp   = (u16*)(ws + OFF_P);
  u16*   PT   = (u16*)(ws + OFF_PT);

  k0_transpose<<<dim3(N_TOK / 64, DIM / 64), 256, 0, stream>>>(X, TX);
  k0_convert_w<<<dim3((NC * DIM) / 1024), 256, 0, stream>>>(W, Wb);
  p1_fused<<<dim3(N_TOK / 64), 256, 0, stream>>>(X, Wb, b, Pp, PT);
  p2_gemm<<<dim3(512), 256, 0, stream>>>(TX, PT, part);
  k2_reduce<<<dim3((DIM * NC) / 1024), 256, 0, stream>>>(part, PtXb);
  p3_gemm<<<dim3(2048), 256, 0, stream>>>(Pp, PtXb, X, Out);
}

// Round 5
// 387.185 us; speedup vs baseline: 1.0477x; 1.0477x over previous
//
#include <hip/hip_runtime.h>
#include <hip/hip_bf16.h>
#include <stdint.h>

#define N_TOK 32768
#define DIM   1024
#define NC    256
#define GAMMA_F 1e-4f

typedef unsigned short u16;
typedef __attribute__((ext_vector_type(8))) short bf16x8;
typedef __attribute__((ext_vector_type(4))) float f32x4;

// float -> bf16 (round-to-nearest-even); inputs are finite
__device__ __forceinline__ u16 f2b(float f) {
  union { float f; uint32_t u; } c; c.f = f;
  uint32_t u = c.u;
  return (u16)((u + 0x7FFFu + ((u >> 16) & 1u)) >> 16);
}

// async global->LDS, 16B per lane; lds arg must be the wave-uniform chunk base
__device__ __forceinline__ void gll16(const void* g, void* l) {
  __builtin_amdgcn_global_load_lds(
      (const __attribute__((address_space(1))) unsigned int*)g,
      (__attribute__((address_space(3))) unsigned int*)l, 16, 0, 0);
}

// Swizzle scheme for [R][64]-bf16 LDS tiles (128B row = 8 x 16B units):
//   slot (row, u) holds global unit u ^ (row&7)  -> conflict-free b128 reads.

// ---------------------------------------------------------------- K0: X^T -> bf16
__global__ __launch_bounds__(256) void k0_transpose(const float* __restrict__ X,
                                                    u16* __restrict__ TX) {
  __shared__ u16 tile[64][68];
  const int n0 = blockIdx.x * 64;
  const int d0 = blockIdx.y * 64;
  const int t = threadIdx.x;
  const int r = t >> 4;
  const int c4 = (t & 15) * 4;
#pragma unroll
  for (int i = 0; i < 4; ++i) {
    const int row = r + i * 16;
    const float4 v = *reinterpret_cast<const float4*>(&X[(size_t)(n0 + row) * DIM + d0 + c4]);
    tile[row][c4 + 0] = f2b(v.x);
    tile[row][c4 + 1] = f2b(v.y);
    tile[row][c4 + 2] = f2b(v.z);
    tile[row][c4 + 3] = f2b(v.w);
  }
  __syncthreads();
#pragma unroll
  for (int i = 0; i < 4; ++i) {
    const int drow = r + i * 16;
    ushort4 o;
    o.x = tile[c4 + 0][drow];
    o.y = tile[c4 + 1][drow];
    o.z = tile[c4 + 2][drow];
    o.w = tile[c4 + 3][drow];
    *reinterpret_cast<ushort4*>(&TX[(size_t)(d0 + drow) * N_TOK + n0 + c4]) = o;
  }
}

// ---------------------------------------------------------------- K0w: W -> bf16
__global__ __launch_bounds__(256) void k0_convert_w(const float* __restrict__ W,
                                                    u16* __restrict__ Wb) {
  const int idx = (blockIdx.x * 256 + threadIdx.x) * 4;
  const float4 v = *reinterpret_cast<const float4*>(&W[idx]);
  ushort4 o;
  o.x = f2b(v.x); o.y = f2b(v.y); o.z = f2b(v.z); o.w = f2b(v.w);
  *reinterpret_cast<ushort4*>(&Wb[idx]) = o;
}

// ---------------------------------------------------------------- P1: S = X*Wb^T -> softmax -> P, P^T
// BM=64, BN=256 (X read ONCE). 4 waves (2m x 2n). Register softmax.
// LDS = 40KB; cap 256 regs (NO tight min-wave: acc+temps ~150 regs, a 128-reg
// cap spills — that was R3's regression).
__global__ __launch_bounds__(256, 2) void p1_fused(const float* __restrict__ X,
                                                   const u16* __restrict__ Wb,
                                                   const float* __restrict__ bias,
                                                   u16* __restrict__ P,
                                                   u16* __restrict__ PT) {
  __shared__ __align__(16) char smem[40960];       // As 8K | Bs 32K ; epilogue: Su 33280 + red 1K
  u16* As = (u16*)smem;                            // [64][64] bf16, swizzled
  u16* Bs = (u16*)(smem + 8192);                   // [256][64] bf16, swizzled
  const int t = threadIdx.x;
  const int lane = t & 63, wave = t >> 6;
  const int wm = wave & 1, wn = wave >> 1;
  const int id = blockIdx.x;
  const int n0 = ((id & 7) * 64 + (id >> 3)) * 64; // XCD-swizzled (512 blocks)
  const int frow = lane & 15, fq = lane >> 4;
  const int au = t & 7, ar0 = t >> 3;              // A staging: unit, row
  const int bug = (lane & 7) ^ (lane >> 3);        // B staging: swizzled global unit

  f32x4 acc[2][8] = {};
  for (int kt = 0; kt < 16; ++kt) {
    const int k0 = kt * 64;
    // A: X f32 [64][64] -> bf16, swizzled ds_write
#pragma unroll
    for (int h = 0; h < 2; ++h) {
      const int r = ar0 + h * 32;
      const size_t gb = (size_t)(n0 + r) * DIM + k0 + au * 8;
      const float4 v0 = *reinterpret_cast<const float4*>(&X[gb]);
      const float4 v1 = *reinterpret_cast<const float4*>(&X[gb + 4]);
      bf16x8 u;
      u[0] = (short)f2b(v0.x); u[1] = (short)f2b(v0.y);
      u[2] = (short)f2b(v0.z); u[3] = (short)f2b(v0.w);
      u[4] = (short)f2b(v1.x); u[5] = (short)f2b(v1.y);
      u[6] = (short)f2b(v1.z); u[7] = (short)f2b(v1.w);
      *reinterpret_cast<bf16x8*>(&As[r * 64 + ((au ^ (r & 7)) * 8)]) = u;
    }
    // B: Wb [256][64] via global_load_lds, pre-swizzled source
#pragma unroll
    for (int i = 0; i < 8; ++i) {
      const int chunk = wave * 8 + i;
      const int brow = chunk * 8 + (lane >> 3);
      gll16(&Wb[(size_t)brow * DIM + k0 + bug * 8], &Bs[chunk * 512]);
    }
    __syncthreads();
#pragma unroll
    for (int ks = 0; ks < 2; ++ks) {
      bf16x8 af[2], bg[8];
#pragma unroll
      for (int m = 0; m < 2; ++m) {
        const int r = wm * 32 + m * 16 + frow;
        af[m] = *reinterpret_cast<const bf16x8*>(&As[r * 64 + (((ks * 4 + fq) ^ (r & 7)) * 8)]);
      }
#pragma unroll
      for (int n = 0; n < 8; ++n) {
        const int r = wn * 128 + n * 16 + frow;
        bg[n] = *reinterpret_cast<const bf16x8*>(&Bs[r * 64 + (((ks * 4 + fq) ^ (r & 7)) * 8)]);
      }
#pragma unroll
      for (int m = 0; m < 2; ++m)
#pragma unroll
        for (int n = 0; n < 8; ++n)
          acc[m][n] = __builtin_amdgcn_mfma_f32_16x16x32_bf16(af[m], bg[n], acc[m][n], 0, 0, 0);
    }
    __syncthreads();
  }

  // ---- register softmax epilogue
  u16*   Su     = (u16*)smem;                      // [64][260] bf16, col^((row&7)<<2) swizzle
  float* red_mx = (float*)(smem + 33280);          // [64][2]
  float* red_sm = (float*)(smem + 33792);          // [64][2]

  float bias_r[8];
#pragma unroll
  for (int n = 0; n < 8; ++n) bias_r[n] = bias[wn * 128 + n * 16 + frow];
#pragma unroll
  for (int m = 0; m < 2; ++m)
#pragma unroll
    for (int n = 0; n < 8; ++n)
#pragma unroll
      for (int j = 0; j < 4; ++j) acc[m][n][j] += bias_r[n];

  float mx[2][4];
#pragma unroll
  for (int m = 0; m < 2; ++m)
#pragma unroll
    for (int j = 0; j < 4; ++j) {
      float v = acc[m][0][j];
#pragma unroll
      for (int n = 1; n < 8; ++n) v = fmaxf(v, acc[m][n][j]);
#pragma unroll
      for (int s = 1; s < 16; s <<= 1) v = fmaxf(v, __shfl_xor(v, s, 64));
      mx[m][j] = v;
    }
  if (frow == 0) {
#pragma unroll
    for (int m = 0; m < 2; ++m)
#pragma unroll
      for (int j = 0; j < 4; ++j)
        red_mx[(wm * 32 + m * 16 + fq * 4 + j) * 2 + wn] = mx[m][j];
  }
  __syncthreads();

  const float l2e = 1.44269504088896f;
  float psum[2][4];
#pragma unroll
  for (int m = 0; m < 2; ++m)
#pragma unroll
    for (int j = 0; j < 4; ++j) {
      const int row = wm * 32 + m * 16 + fq * 4 + j;
      const float2 r2 = *reinterpret_cast<const float2*>(&red_mx[row * 2]);
      const float M = fmaxf(r2.x, r2.y);
      float s = 0.f;
#pragma unroll
      for (int n = 0; n < 8; ++n) {
        const float e = exp2f((acc[m][n][j] - M) * l2e);
        acc[m][n][j] = e;
        s += e;
      }
#pragma unroll
      for (int ss = 1; ss < 16; ss <<= 1) s += __shfl_xor(s, ss, 64);
      psum[m][j] = s;
    }
  if (frow == 0) {
#pragma unroll
    for (int m = 0; m < 2; ++m)
#pragma unroll
      for (int j = 0; j < 4; ++j)
        red_sm[(wm * 32 + m * 16 + fq * 4 + j) * 2 + wn] = psum[m][j];
  }
  __syncthreads();

#pragma unroll
  for (int m = 0; m < 2; ++m)
#pragma unroll
    for (int j = 0; j < 4; ++j) {
      const int row = wm * 32 + m * 16 + fq * 4 + j;
      const float2 r2 = *reinterpret_cast<const float2*>(&red_sm[row * 2]);
      const float iv = 1.0f / (r2.x + r2.y);
      const int sw = (row & 7) << 2;
#pragma unroll
      for (int n = 0; n < 8; ++n)
        Su[row * 260 + ((wn * 128 + n * 16 + frow) ^ sw)] = f2b(acc[m][n][j] * iv);
    }
  __syncthreads();

  // P: coalesced, 256 threads x ushort4 (XOR is 4-col-granular -> aligned)
#pragma unroll
  for (int g = 0; g < 16; ++g) {
    const int row = g * 4 + wave;
    const int c = lane * 4;
    const ushort4 v = *reinterpret_cast<const ushort4*>(&Su[row * 260 + (c ^ ((row & 7) << 2))]);
    *reinterpret_cast<ushort4*>(&P[(size_t)(n0 + row) * NC + c]) = v;
  }
  // PT: quarter-wave per c-row, 16 lanes x ushort4 = 128B contiguous
#pragma unroll
  for (int it = 0; it < 16; ++it) {
    const int c = it * 16 + wave * 4 + fq;
    const int n = frow * 4;
    ushort4 o;
    o.x = Su[(n + 0) * 260 + (c ^ (((n + 0) & 7) << 2))];
    o.y = Su[(n + 1) * 260 + (c ^ (((n + 1) & 7) << 2))];
    o.z = Su[(n + 2) * 260 + (c ^ (((n + 2) & 7) << 2))];
    o.w = Su[(n + 3) * 260 + (c ^ (((n + 3) & 7) << 2))];
    *reinterpret_cast<ushort4*>(&PT[(size_t)c * N_TOK + n0 + n]) = o;
  }
}

// ---------------------------------------------------------------- P2: PtX^T partials = TX * PT^T (split-K)
// LDS 34KB; (256,3): cap 170 regs, footprint ~132 (R1-measured) -> no spill.
__global__ __launch_bounds__(256, 3) void p2_gemm(const u16* __restrict__ TX,
                                                  const u16* __restrict__ PT,
                                                  float* __restrict__ part) {
  __shared__ __align__(16) char smem[34816];       // As 16K + Bs 16K ; Cf half 33792
  u16* As = (u16*)smem;
  u16* Bs = (u16*)(smem + 16384);
  const int t = threadIdx.x;
  const int lane = t & 63, wave = t >> 6;
  const int wm = wave & 1, wn = wave >> 1;
  const int id = blockIdx.x;                       // 512 blocks 1D
  const int swz = (id & 7) * 64 + (id >> 3);
  const int d0 = (swz & 7) * 128;                  // fastest -> blocks share PT tile
  const int sk = (swz >> 3) & 31;
  const int c0 = (swz >> 8) * 128;
  const int frow = lane & 15, fq = lane >> 4;
  const int srow = lane >> 3;
  const int bug = (lane & 7) ^ (lane >> 3);
  f32x4 acc[4][4] = {};
  for (int kt = 0; kt < 16; ++kt) {
    const size_t k0 = (size_t)sk * 1024 + kt * 64;
#pragma unroll
    for (int i = 0; i < 4; ++i) {
      const int chunk = wave * 4 + i;
      const int r = chunk * 8 + srow;
      gll16(&TX[(size_t)(d0 + r) * N_TOK + k0 + bug * 8], &As[chunk * 512]);
      gll16(&PT[(size_t)(c0 + r) * N_TOK + k0 + bug * 8], &Bs[chunk * 512]);
    }
    __syncthreads();
#pragma unroll
    for (int ks = 0; ks < 2; ++ks) {
      bf16x8 af[4], bg[4];
#pragma unroll
      for (int m = 0; m < 4; ++m) {
        const int r = wm * 64 + m * 16 + frow;
        af[m] = *reinterpret_cast<const bf16x8*>(&As[r * 64 + (((ks * 4 + fq) ^ (r & 7)) * 8)]);
      }
#pragma unroll
      for (int n = 0; n < 4; ++n) {
        const int r = wn * 64 + n * 16 + frow;
        bg[n] = *reinterpret_cast<const bf16x8*>(&Bs[r * 64 + (((ks * 4 + fq) ^ (r & 7)) * 8)]);
      }
#pragma unroll
      for (int m = 0; m < 4; ++m)
#pragma unroll
        for (int n = 0; n < 4; ++n)
          acc[m][n] = __builtin_amdgcn_mfma_f32_16x16x32_bf16(af[m], bg[n], acc[m][n], 0, 0, 0);
    }
    __syncthreads();
  }
  // epilogue in two 64-row halves (Cf aliases As+Bs)
  float* Cf = (float*)smem;                        // [64][132]
  float* pl = part + (size_t)sk * (DIM * NC);
  const int cl = (t & 31) * 4;
  const int rq = t >> 5;
#pragma unroll
  for (int h = 0; h < 2; ++h) {
    __syncthreads();
    if (wm == h) {
#pragma unroll
      for (int m = 0; m < 4; ++m)
#pragma unroll
        for (int n = 0; n < 4; ++n) {
          const int rr = m * 16 + fq * 4;
          const int col = wn * 64 + n * 16 + frow;
#pragma unroll
          for (int j = 0; j < 4; ++j)
            Cf[(rr + j) * 132 + col] = acc[m][n][j];
        }
    }
    __syncthreads();
#pragma unroll
    for (int p = 0; p < 8; ++p) {
      const int row = p * 8 + rq;
      const float4 v = *reinterpret_cast<const float4*>(&Cf[row * 132 + cl]);
      *reinterpret_cast<float4*>(&pl[(size_t)(d0 + h * 64 + row) * NC + c0 + cl]) = v;
    }
  }
}

// ---------------------------------------------------------------- K2r: reduce split-K, fold gamma, -> bf16
__global__ __launch_bounds__(256) void k2_reduce(const float* __restrict__ part,
                                                 u16* __restrict__ PtXb) {
  const int g = (blockIdx.x * 256 + threadIdx.x) * 4;
  f32x4 s = {0.f, 0.f, 0.f, 0.f};
#pragma unroll
  for (int p = 0; p < 32; ++p)
    s += *reinterpret_cast<const f32x4*>(&part[(size_t)p * (DIM * NC) + g]);
  ushort4 o;
  o.x = f2b(s[0] * GAMMA_F); o.y = f2b(s[1] * GAMMA_F);
  o.z = f2b(s[2] * GAMMA_F); o.w = f2b(s[3] * GAMMA_F);
  *reinterpret_cast<ushort4*>(&PtXb[g]) = o;
}

// ---------------------------------------------------------------- P3: Out = X + P * PtXb^T
// LDS 34KB; (256,3) -> 3 blocks/CU, no spill. One d-panel per XCD.
__global__ __launch_bounds__(256, 3) void p3_gemm(const u16* __restrict__ P,
                                                  const u16* __restrict__ PtXb,
                                                  const float* __restrict__ X,
                                                  float* __restrict__ Out) {
  __shared__ __align__(16) char smem[34816];
  u16* As = (u16*)smem;
  u16* Bs = (u16*)(smem + 16384);
  const int t = threadIdx.x;
  const int lane = t & 63, wave = t >> 6;
  const int wm = wave & 1, wn = wave >> 1;
  const int id = blockIdx.x;                       // 2048 blocks 1D
  const int swz = (id & 7) * 256 + (id >> 3);
  const int n0 = (swz & 255) * 128;                // fastest -> PtXb panel L2-resident
  const int d0 = (swz >> 8) * 128;
  const int frow = lane & 15, fq = lane >> 4;
  const int srow = lane >> 3;
  const int bug = (lane & 7) ^ (lane >> 3);
  f32x4 acc[4][4] = {};
  for (int kt = 0; kt < 4; ++kt) {
    const int k0 = kt * 64;
#pragma unroll
    for (int i = 0; i < 4; ++i) {
      const int chunk = wave * 4 + i;
      const int r = chunk * 8 + srow;
      gll16(&P[(size_t)(n0 + r) * NC + k0 + bug * 8], &As[chunk * 512]);
      gll16(&PtXb[(size_t)(d0 + r) * NC + k0 + bug * 8], &Bs[chunk * 512]);
    }
    __syncthreads();
#pragma unroll
    for (int ks = 0; ks < 2; ++ks) {
      bf16x8 af[4], bg[4];
#pragma unroll
      for (int m = 0; m < 4; ++m) {
        const int r = wm * 64 + m * 16 + frow;
        af[m] = *reinterpret_cast<const bf16x8*>(&As[r * 64 + (((ks * 4 + fq) ^ (r & 7)) * 8)]);
      }
#pragma unroll
      for (int n = 0; n < 4; ++n) {
        const int r = wn * 64 + n * 16 + frow;
        bg[n] = *reinterpret_cast<const bf16x8*>(&Bs[r * 64 + (((ks * 4 + fq) ^ (r & 7)) * 8)]);
      }
#pragma unroll
      for (int m = 0; m < 4; ++m)
#pragma unroll
        for (int n = 0; n < 4; ++n)
          acc[m][n] = __builtin_amdgcn_mfma_f32_16x16x32_bf16(af[m], bg[n], acc[m][n], 0, 0, 0);
    }
    __syncthreads();
  }
  // epilogue in two 64-row halves: coalesced float4 X-read + Out-write
  float* Cf = (float*)smem;                        // [64][132]
  const int cl = (t & 31) * 4;
  const int rq = t >> 5;
#pragma unroll
  for (int h = 0; h < 2; ++h) {
    __syncthreads();
    if (wm == h) {
#pragma unroll
      for (int m = 0; m < 4; ++m)
#pragma unroll
        for (int n = 0; n < 4; ++n) {
          const int rr = m * 16 + fq * 4;
          const int col = wn * 64 + n * 16 + frow;
#pragma unroll
          for (int j = 0; j < 4; ++j)
            Cf[(rr + j) * 132 + col] = acc[m][n][j];
        }
    }
    __syncthreads();
#pragma unroll
    for (int p = 0; p < 8; ++p) {
      const int row = p * 8 + rq;
      float4 v = *reinterpret_cast<const float4*>(&Cf[row * 132 + cl]);
      const size_t off = (size_t)(n0 + h * 64 + row) * DIM + d0 + cl;
      const float4 x = *reinterpret_cast<const float4*>(&X[off]);
      v.x += x.x; v.y += x.y; v.z += x.z; v.w += x.w;
      *reinterpret_cast<float4*>(&Out[off]) = v;
    }
  }
}

// ---------------------------------------------------------------- launch
extern "C" void kernel_launch(void* const* d_in, const int* in_sizes, int n_in,
                              void* d_out, int out_size, void* d_ws, size_t ws_size,
                              hipStream_t stream) {
  const float* X = (const float*)d_in[0];
  const float* W = (const float*)d_in[1];
  const float* b = (const float*)d_in[2];
  float* Out = (float*)d_out;
  char* ws = (char*)d_ws;

  // ws layout (bytes): TX 64MB | Wb 0.5MB | PtXb 0.5MB | partials 32MB | P 16MB | PT 16MB
  const size_t OFF_TX   = 0;
  const size_t OFF_WB   = (size_t)64 << 20;
  const size_t OFF_PTXB = OFF_WB + ((size_t)512 << 10);
  const size_t OFF_PART = (size_t)65 << 20;
  const size_t OFF_P    = (size_t)97 << 20;
  const size_t OFF_PT   = (size_t)113 << 20;
  const size_t NEED     = (size_t)129 << 20;
  if (ws_size < NEED) return;

  u16*   TX   = (u16*)(ws + OFF_TX);
  u16*   Wb   = (u16*)(ws + OFF_WB);
  u16*   PtXb = (u16*)(ws + OFF_PTXB);
  float* part = (float*)(ws + OFF_PART);
  u16*   Pp   = (u16*)(ws + OFF_P);
  u16*   PT   = (u16*)(ws + OFF_PT);

  k0_transpose<<<dim3(N_TOK / 64, DIM / 64), 256, 0, stream>>>(X, TX);
  k0_convert_w<<<dim3((NC * DIM) / 1024), 256, 0, stream>>>(W, Wb);
  p1_fused<<<dim3(N_TOK / 64), 256, 0, stream>>>(X, Wb, b, Pp, PT);
  p2_gemm<<<dim3(512), 256, 0, stream>>>(TX, PT, part);
  k2_reduce<<<dim3((DIM * NC) / 1024), 256, 0, stream>>>(part, PtXb);
  p3_gemm<<<dim3(2048), 256, 0, stream>>>(Pp, PtXb, X, Out);
}

// Round 7
// 354.024 us; speedup vs baseline: 1.1459x; 1.0937x over previous
//
#include <hip/hip_runtime.h>
#include <hip/hip_bf16.h>
#include <stdint.h>

#define N_TOK 32768
#define DIM   1024
#define NC    256
#define GAMMA_F 1e-4f

typedef unsigned short u16;
typedef __attribute__((ext_vector_type(8))) short bf16x8;
typedef __attribute__((ext_vector_type(4))) float f32x4;

// float -> bf16 (round-to-nearest-even); inputs are finite
__device__ __forceinline__ u16 f2b(float f) {
  union { float f; uint32_t u; } c; c.f = f;
  uint32_t u = c.u;
  return (u16)((u + 0x7FFFu + ((u >> 16) & 1u)) >> 16);
}

// async global->LDS, 16B per lane; lds arg must be the wave-uniform chunk base
__device__ __forceinline__ void gll16(const void* g, void* l) {
  __builtin_amdgcn_global_load_lds(
      (const __attribute__((address_space(1))) unsigned int*)g,
      (__attribute__((address_space(3))) unsigned int*)l, 16, 0, 0);
}

// Swizzle scheme for [R][64]-bf16 LDS tiles (128B row = 8 x 16B units):
//   slot (row, u) holds global unit u ^ (row&7)  -> conflict-free b128 reads.

// ---------------------------------------------------------------- K0w: W -> bf16
__global__ __launch_bounds__(256) void k0_convert_w(const float* __restrict__ W,
                                                    u16* __restrict__ Wb) {
  const int idx = (blockIdx.x * 256 + threadIdx.x) * 4;
  const float4 v = *reinterpret_cast<const float4*>(&W[idx]);
  ushort4 o;
  o.x = f2b(v.x); o.y = f2b(v.y); o.z = f2b(v.z); o.w = f2b(v.w);
  *reinterpret_cast<ushort4*>(&Wb[idx]) = o;
}

// ---------------------------------------------------------------- P1: S = X*Wb^T -> softmax -> P, P^T
// BM=64, BN=256 (X read ONCE). 4 waves (2m x 2n). Register softmax.
// ~132 regs -> 3 waves/SIMD natural; LDS 40KB -> 3 blocks/CU.
__global__ __launch_bounds__(256, 2) void p1_fused(const float* __restrict__ X,
                                                   const u16* __restrict__ Wb,
                                                   const float* __restrict__ bias,
                                                   u16* __restrict__ P,
                                                   u16* __restrict__ PT) {
  __shared__ __align__(16) char smem[40960];       // As 8K | Bs 32K ; epilogue: Su 33280 + red 1K
  u16* As = (u16*)smem;                            // [64][64] bf16, swizzled
  u16* Bs = (u16*)(smem + 8192);                   // [256][64] bf16, swizzled
  const int t = threadIdx.x;
  const int lane = t & 63, wave = t >> 6;
  const int wm = wave & 1, wn = wave >> 1;
  const int id = blockIdx.x;
  const int n0 = ((id & 7) * 64 + (id >> 3)) * 64; // XCD-swizzled (512 blocks)
  const int frow = lane & 15, fq = lane >> 4;
  const int au = t & 7, ar0 = t >> 3;              // A staging: unit, row
  const int bug = (lane & 7) ^ (lane >> 3);        // B staging: swizzled global unit

  f32x4 acc[2][8] = {};
  for (int kt = 0; kt < 16; ++kt) {
    const int k0 = kt * 64;
    // A: X f32 [64][64] -> bf16, swizzled ds_write
#pragma unroll
    for (int h = 0; h < 2; ++h) {
      const int r = ar0 + h * 32;
      const size_t gb = (size_t)(n0 + r) * DIM + k0 + au * 8;
      const float4 v0 = *reinterpret_cast<const float4*>(&X[gb]);
      const float4 v1 = *reinterpret_cast<const float4*>(&X[gb + 4]);
      bf16x8 u;
      u[0] = (short)f2b(v0.x); u[1] = (short)f2b(v0.y);
      u[2] = (short)f2b(v0.z); u[3] = (short)f2b(v0.w);
      u[4] = (short)f2b(v1.x); u[5] = (short)f2b(v1.y);
      u[6] = (short)f2b(v1.z); u[7] = (short)f2b(v1.w);
      *reinterpret_cast<bf16x8*>(&As[r * 64 + ((au ^ (r & 7)) * 8)]) = u;
    }
    // B: Wb [256][64] via global_load_lds, pre-swizzled source
#pragma unroll
    for (int i = 0; i < 8; ++i) {
      const int chunk = wave * 8 + i;
      const int brow = chunk * 8 + (lane >> 3);
      gll16(&Wb[(size_t)brow * DIM + k0 + bug * 8], &Bs[chunk * 512]);
    }
    __syncthreads();
#pragma unroll
    for (int ks = 0; ks < 2; ++ks) {
      bf16x8 af[2], bg[8];
#pragma unroll
      for (int m = 0; m < 2; ++m) {
        const int r = wm * 32 + m * 16 + frow;
        af[m] = *reinterpret_cast<const bf16x8*>(&As[r * 64 + (((ks * 4 + fq) ^ (r & 7)) * 8)]);
      }
#pragma unroll
      for (int n = 0; n < 8; ++n) {
        const int r = wn * 128 + n * 16 + frow;
        bg[n] = *reinterpret_cast<const bf16x8*>(&Bs[r * 64 + (((ks * 4 + fq) ^ (r & 7)) * 8)]);
      }
#pragma unroll
      for (int m = 0; m < 2; ++m)
#pragma unroll
        for (int n = 0; n < 8; ++n)
          acc[m][n] = __builtin_amdgcn_mfma_f32_16x16x32_bf16(af[m], bg[n], acc[m][n], 0, 0, 0);
    }
    __syncthreads();
  }

  // ---- register softmax epilogue
  u16*   Su     = (u16*)smem;                      // [64][260] bf16, col^((row&7)<<2) swizzle
  float* red_mx = (float*)(smem + 33280);          // [64][2]
  float* red_sm = (float*)(smem + 33792);          // [64][2]

  float bias_r[8];
#pragma unroll
  for (int n = 0; n < 8; ++n) bias_r[n] = bias[wn * 128 + n * 16 + frow];
#pragma unroll
  for (int m = 0; m < 2; ++m)
#pragma unroll
    for (int n = 0; n < 8; ++n)
#pragma unroll
      for (int j = 0; j < 4; ++j) acc[m][n][j] += bias_r[n];

  float mx[2][4];
#pragma unroll
  for (int m = 0; m < 2; ++m)
#pragma unroll
    for (int j = 0; j < 4; ++j) {
      float v = acc[m][0][j];
#pragma unroll
      for (int n = 1; n < 8; ++n) v = fmaxf(v, acc[m][n][j]);
#pragma unroll
      for (int s = 1; s < 16; s <<= 1) v = fmaxf(v, __shfl_xor(v, s, 64));
      mx[m][j] = v;
    }
  if (frow == 0) {
#pragma unroll
    for (int m = 0; m < 2; ++m)
#pragma unroll
      for (int j = 0; j < 4; ++j)
        red_mx[(wm * 32 + m * 16 + fq * 4 + j) * 2 + wn] = mx[m][j];
  }
  __syncthreads();

  const float l2e = 1.44269504088896f;
  float psum[2][4];
#pragma unroll
  for (int m = 0; m < 2; ++m)
#pragma unroll
    for (int j = 0; j < 4; ++j) {
      const int row = wm * 32 + m * 16 + fq * 4 + j;
      const float2 r2 = *reinterpret_cast<const float2*>(&red_mx[row * 2]);
      const float M = fmaxf(r2.x, r2.y);
      float s = 0.f;
#pragma unroll
      for (int n = 0; n < 8; ++n) {
        const float e = exp2f((acc[m][n][j] - M) * l2e);
        acc[m][n][j] = e;
        s += e;
      }
#pragma unroll
      for (int ss = 1; ss < 16; ss <<= 1) s += __shfl_xor(s, ss, 64);
      psum[m][j] = s;
    }
  if (frow == 0) {
#pragma unroll
    for (int m = 0; m < 2; ++m)
#pragma unroll
      for (int j = 0; j < 4; ++j)
        red_sm[(wm * 32 + m * 16 + fq * 4 + j) * 2 + wn] = psum[m][j];
  }
  __syncthreads();

#pragma unroll
  for (int m = 0; m < 2; ++m)
#pragma unroll
    for (int j = 0; j < 4; ++j) {
      const int row = wm * 32 + m * 16 + fq * 4 + j;
      const float2 r2 = *reinterpret_cast<const float2*>(&red_sm[row * 2]);
      const float iv = 1.0f / (r2.x + r2.y);
      const int sw = (row & 7) << 2;
#pragma unroll
      for (int n = 0; n < 8; ++n)
        Su[row * 260 + ((wn * 128 + n * 16 + frow) ^ sw)] = f2b(acc[m][n][j] * iv);
    }
  __syncthreads();

  // P: coalesced, 256 threads x ushort4 (XOR is 4-col-granular -> aligned)
#pragma unroll
  for (int g = 0; g < 16; ++g) {
    const int row = g * 4 + wave;
    const int c = lane * 4;
    const ushort4 v = *reinterpret_cast<const ushort4*>(&Su[row * 260 + (c ^ ((row & 7) << 2))]);
    *reinterpret_cast<ushort4*>(&P[(size_t)(n0 + row) * NC + c]) = v;
  }
  // PT: quarter-wave per c-row, 16 lanes x ushort4 = 128B contiguous
#pragma unroll
  for (int it = 0; it < 16; ++it) {
    const int c = it * 16 + wave * 4 + fq;
    const int n = frow * 4;
    ushort4 o;
    o.x = Su[(n + 0) * 260 + (c ^ (((n + 0) & 7) << 2))];
    o.y = Su[(n + 1) * 260 + (c ^ (((n + 1) & 7) << 2))];
    o.z = Su[(n + 2) * 260 + (c ^ (((n + 2) & 7) << 2))];
    o.w = Su[(n + 3) * 260 + (c ^ (((n + 3) & 7) << 2))];
    *reinterpret_cast<ushort4*>(&PT[(size_t)c * N_TOK + n0 + n]) = o;
  }
}

// ---------------------------------------------------------------- P2: PtX^T partials = X^T * P (split-K over n)
// Reads X DIRECTLY (no k0/TX detour): reg-stage f32, pair-pack bf16, transposed
// swizzled ds_write_b32 (<=4-way write conflict; reads unchanged/conflict-free).
// Tile: 64d x 256c, K-chunk 1024 (32 sk planes) -> 512 blocks. X read ONCE.
__global__ __launch_bounds__(256, 3) void p2_direct(const float* __restrict__ X,
                                                    const u16* __restrict__ PT,
                                                    float* __restrict__ part) {
  __shared__ __align__(16) char smem[40960];       // As 8K | Bs 32K ; epilogue Cf 33280
  u16* As = (u16*)smem;                            // [64 d][64 k] swizzled
  u16* Bs = (u16*)(smem + 8192);                   // [256 c][64 k] swizzled
  const int t = threadIdx.x;
  const int lane = t & 63, wave = t >> 6;          // wave = c-quadrant (4 waves x 64c)
  const int id = blockIdx.x;                       // 512 blocks 1D
  const int wgid = (id & 7) * 64 + (id >> 3);      // XCD-chunked: same-sk blocks colocate
  const int d0 = (wgid & 15) * 64;
  const int sk = wgid >> 4;                        // 0..31
  const int frow = lane & 15, fq = lane >> 4;
  const int dloc = t & 31;                         // staging: 32 consecutive d
  const int kp = t >> 5;                           // staging: k-pair index 0..7
  const int bug = (lane & 7) ^ (lane >> 3);
  f32x4 acc[4][4] = {};
  for (int kt = 0; kt < 16; ++kt) {
    const size_t nb = (size_t)sk * 1024 + kt * 64; // n-base of this K-tile
    // A: X[n][d] -> As[d][n-local] bf16 (transpose in staging)
#pragma unroll
    for (int pass = 0; pass < 4; ++pass) {
      const int kk = pass * 16 + kp * 2;           // even k-local
#pragma unroll
      for (int jj = 0; jj < 2; ++jj) {
        const int d = dloc + jj * 32;
        const float x0 = X[(nb + kk) * DIM + d0 + d];
        const float x1 = X[(nb + kk + 1) * DIM + d0 + d];
        const uint32_t pk = (uint32_t)f2b(x0) | ((uint32_t)f2b(x1) << 16);
        *reinterpret_cast<uint32_t*>(&As[d * 64 + (((kk >> 3) ^ (d & 7)) * 8) + (kk & 7)]) = pk;
      }
    }
    // B: PT [256][64] via gll16 (k = n is contiguous in PT rows)
#pragma unroll
    for (int i = 0; i < 16; ++i) {
      const int ch = wave * 16 + i;
      const int c = ch * 8 + (lane >> 3);
      gll16(&PT[(size_t)c * N_TOK + nb + bug * 8], &Bs[ch * 512]);
    }
    __syncthreads();
#pragma unroll
    for (int ks = 0; ks < 2; ++ks) {
      bf16x8 af[4], bg[4];
#pragma unroll
      for (int m = 0; m < 4; ++m) {
        const int r = m * 16 + frow;               // d-row (all waves share As)
        af[m] = *reinterpret_cast<const bf16x8*>(&As[r * 64 + (((ks * 4 + fq) ^ (r & 7)) * 8)]);
      }
#pragma unroll
      for (int n = 0; n < 4; ++n) {
        const int r = wave * 64 + n * 16 + frow;   // c-row
        bg[n] = *reinterpret_cast<const bf16x8*>(&Bs[r * 64 + (((ks * 4 + fq) ^ (r & 7)) * 8)]);
      }
#pragma unroll
      for (int m = 0; m < 4; ++m)
#pragma unroll
        for (int n = 0; n < 4; ++n)
          acc[m][n] = __builtin_amdgcn_mfma_f32_16x16x32_bf16(af[m], bg[n], acc[m][n], 0, 0, 0);
    }
    __syncthreads();
  }
  // epilogue: two 32-d-row phases through LDS, coalesced f32x4 stores
  float* Cf = (float*)smem;                        // [32][260]
  float* pl = part + (size_t)sk * (DIM * NC);
  const int cl = (t & 63) * 4;
  const int rr = t >> 6;
#pragma unroll
  for (int h = 0; h < 2; ++h) {
    __syncthreads();
#pragma unroll
    for (int mm = 0; mm < 2; ++mm) {
      const int m = h * 2 + mm;
#pragma unroll
      for (int n = 0; n < 4; ++n) {
        const int rloc = mm * 16 + fq * 4;
        const int col = wave * 64 + n * 16 + frow;
#pragma unroll
        for (int j = 0; j < 4; ++j)
          Cf[(rloc + j) * 260 + col] = acc[m][n][j];
      }
    }
    __syncthreads();
#pragma unroll
    for (int p = 0; p < 8; ++p) {
      const int row = p * 4 + rr;
      const f32x4 v = *reinterpret_cast<const f32x4*>(&Cf[row * 260 + cl]);
      *reinterpret_cast<f32x4*>(&pl[(size_t)(d0 + h * 32 + row) * NC + cl]) = v;
    }
  }
}

// ---------------------------------------------------------------- K2r: reduce split-K, fold gamma, -> bf16
__global__ __launch_bounds__(256) void k2_reduce(const float* __restrict__ part,
                                                 u16* __restrict__ PtXb) {
  const int g = (blockIdx.x * 256 + threadIdx.x) * 4;
  f32x4 s = {0.f, 0.f, 0.f, 0.f};
#pragma unroll
  for (int p = 0; p < 32; ++p)
    s += *reinterpret_cast<const f32x4*>(&part[(size_t)p * (DIM * NC) + g]);
  ushort4 o;
  o.x = f2b(s[0] * GAMMA_F); o.y = f2b(s[1] * GAMMA_F);
  o.z = f2b(s[2] * GAMMA_F); o.w = f2b(s[3] * GAMMA_F);
  *reinterpret_cast<ushort4*>(&PtXb[g]) = o;
}

// ---------------------------------------------------------------- P3: Out = X + P * PtXb^T
__global__ __launch_bounds__(256, 3) void p3_gemm(const u16* __restrict__ P,
                                                  const u16* __restrict__ PtXb,
                                                  const float* __restrict__ X,
                                                  float* __restrict__ Out) {
  __shared__ __align__(16) char smem[34816];
  u16* As = (u16*)smem;
  u16* Bs = (u16*)(smem + 16384);
  const int t = threadIdx.x;
  const int lane = t & 63, wave = t >> 6;
  const int wm = wave & 1, wn = wave >> 1;
  const int id = blockIdx.x;                       // 2048 blocks 1D
  const int swz = (id & 7) * 256 + (id >> 3);
  const int n0 = (swz & 255) * 128;                // fastest -> PtXb panel L2-resident
  const int d0 = (swz >> 8) * 128;
  const int frow = lane & 15, fq = lane >> 4;
  const int srow = lane >> 3;
  const int bug = (lane & 7) ^ (lane >> 3);
  f32x4 acc[4][4] = {};
  for (int kt = 0; kt < 4; ++kt) {
    const int k0 = kt * 64;
#pragma unroll
    for (int i = 0; i < 4; ++i) {
      const int chunk = wave * 4 + i;
      const int r = chunk * 8 + srow;
      gll16(&P[(size_t)(n0 + r) * NC + k0 + bug * 8], &As[chunk * 512]);
      gll16(&PtXb[(size_t)(d0 + r) * NC + k0 + bug * 8], &Bs[chunk * 512]);
    }
    __syncthreads();
#pragma unroll
    for (int ks = 0; ks < 2; ++ks) {
      bf16x8 af[4], bg[4];
#pragma unroll
      for (int m = 0; m < 4; ++m) {
        const int r = wm * 64 + m * 16 + frow;
        af[m] = *reinterpret_cast<const bf16x8*>(&As[r * 64 + (((ks * 4 + fq) ^ (r & 7)) * 8)]);
      }
#pragma unroll
      for (int n = 0; n < 4; ++n) {
        const int r = wn * 64 + n * 16 + frow;
        bg[n] = *reinterpret_cast<const bf16x8*>(&Bs[r * 64 + (((ks * 4 + fq) ^ (r & 7)) * 8)]);
      }
#pragma unroll
      for (int m = 0; m < 4; ++m)
#pragma unroll
        for (int n = 0; n < 4; ++n)
          acc[m][n] = __builtin_amdgcn_mfma_f32_16x16x32_bf16(af[m], bg[n], acc[m][n], 0, 0, 0);
    }
    __syncthreads();
  }
  // epilogue in two 64-row halves: coalesced float4 X-read + Out-write
  float* Cf = (float*)smem;                        // [64][132]
  const int cl = (t & 31) * 4;
  const int rq = t >> 5;
#pragma unroll
  for (int h = 0; h < 2; ++h) {
    __syncthreads();
    if (wm == h) {
#pragma unroll
      for (int m = 0; m < 4; ++m)
#pragma unroll
        for (int n = 0; n < 4; ++n) {
          const int rr = m * 16 + fq * 4;
          const int col = wn * 64 + n * 16 + frow;
#pragma unroll
          for (int j = 0; j < 4; ++j)
            Cf[(rr + j) * 132 + col] = acc[m][n][j];
        }
    }
    __syncthreads();
#pragma unroll
    for (int p = 0; p < 8; ++p) {
      const int row = p * 8 + rq;
      float4 v = *reinterpret_cast<const float4*>(&Cf[row * 132 + cl]);
      const size_t off = (size_t)(n0 + h * 64 + row) * DIM + d0 + cl;
      const float4 x = *reinterpret_cast<const float4*>(&X[off]);
      v.x += x.x; v.y += x.y; v.z += x.z; v.w += x.w;
      *reinterpret_cast<float4*>(&Out[off]) = v;
    }
  }
}

// ---------------------------------------------------------------- launch
extern "C" void kernel_launch(void* const* d_in, const int* in_sizes, int n_in,
                              void* d_out, int out_size, void* d_ws, size_t ws_size,
                              hipStream_t stream) {
  const float* X = (const float*)d_in[0];
  const float* W = (const float*)d_in[1];
  const float* b = (const float*)d_in[2];
  float* Out = (float*)d_out;
  char* ws = (char*)d_ws;

  // ws layout (bytes): Wb 0.5MB | PtXb 0.5MB | partials 32MB | P 16MB | PT 16MB
  const size_t OFF_WB   = 0;
  const size_t OFF_PTXB = (size_t)512 << 10;
  const size_t OFF_PART = (size_t)1 << 20;
  const size_t OFF_P    = (size_t)34 << 20;
  const size_t OFF_PT   = (size_t)50 << 20;
  const size_t NEED     = (size_t)66 << 20;
  if (ws_size < NEED) return;

  u16*   Wb   = (u16*)(ws + OFF_WB);
  u16*   PtXb = (u16*)(ws + OFF_PTXB);
  float* part = (float*)(ws + OFF_PART);
  u16*   Pp   = (u16*)(ws + OFF_P);
  u16*   PT   = (u16*)(ws + OFF_PT);

  k0_convert_w<<<dim3((NC * DIM) / 1024), 256, 0, stream>>>(W, Wb);
  p1_fused<<<dim3(N_TOK / 64), 256, 0, stream>>>(X, Wb, b, Pp, PT);
  p2_direct<<<dim3(512), 256, 0, stream>>>(X, PT, part);
  k2_reduce<<<dim3((DIM * NC) / 1024), 256, 0, stream>>>(part, PtXb);
  p3_gemm<<<dim3(2048), 256, 0, stream>>>(Pp, PtXb, X, Out);
}